// Round 12
// baseline (414.823 us; speedup 1.0000x reference)
//
#include <hip/hip_runtime.h>

#define NB 8
#define IC 64
#define OC 64
#define HH 256
#define WD 512
#define PP 258 // padded pitch

typedef __bf16 bf16x8 __attribute__((ext_vector_type(8)));
typedef float f32x16 __attribute__((ext_vector_type(16)));
typedef float f32x2 __attribute__((ext_vector_type(2)));

// Weight math: modulate, demodulate, compose with blur into E[6][6].
__device__ inline void compute_E(const float* __restrict__ w_conv, float stv,
                                 int oc, float E[6][6]) {
  const float coef_conv = 1.0f / 24.0f; // 1/sqrt(3*3*64)
  const float s = stv * coef_conv;
  const int ic = threadIdx.x & 63;

  float wm[3][3];
  float ssq = 0.f;
  #pragma unroll
  for (int kh = 0; kh < 3; ++kh)
    #pragma unroll
    for (int kw = 0; kw < 3; ++kw) {
      float v = w_conv[((kh * 3 + kw) * IC + ic) * OC + oc] * s;
      wm[kh][kw] = v;
      ssq += v * v;
    }
  #pragma unroll
  for (int off = 32; off > 0; off >>= 1) ssq += __shfl_xor(ssq, off);
  const float d = rsqrtf(ssq + 1e-8f);
  #pragma unroll
  for (int kh = 0; kh < 3; ++kh)
    #pragma unroll
    for (int kw = 0; kw < 3; ++kw) wm[kh][kw] *= d;

  const float g[4] = {0.25f, 0.75f, 0.75f, 0.25f};
  #pragma unroll
  for (int a = 0; a < 6; ++a)
    #pragma unroll
    for (int c = 0; c < 6; ++c) {
      float acc = 0.f;
      #pragma unroll
      for (int dh = 0; dh < 3; ++dh) {
        int u = a - dh;
        if (u < 0 || u > 3) continue;
        #pragma unroll
        for (int dw = 0; dw < 3; ++dw) {
          int v = c - dw;
          if (v < 0 || v > 3) continue;
          acc = fmaf(wm[dh][dw], g[u] * g[v], acc);
        }
      }
      E[a][c] = acc;
    }
}

__device__ inline float style_of(const float* __restrict__ w,
                                 const float* __restrict__ w_dense,
                                 const float* __restrict__ b_mod, int b,
                                 int ic) {
  const float coef_dense = 0.044194173824159216f; // 1/sqrt(512)
  const float* wr = w + b * WD;
  float acc = 0.f;
  for (int k = 0; k < WD; ++k) acc = fmaf(wr[k], w_dense[k * IC + ic], acc);
  return acc * coef_dense + b_mod[ic] + 1.0f;
}

// ---- fused pre-pass: xtp role (bid<2056) + pwfs role (bid>=2056) ----
// xtp: x [b][ic][m][n] f32 -> padded xTg [b][258][258][ic] bf16 (+guard)
// pwfs: PWf frag idx = ph*72 + tap*8 + ocg*4 + ks; 64 lanes x 16B each.
#define XS 268 // u16 LDS stride
__global__ __launch_bounds__(256) void pre_kernel(
    const float* __restrict__ x, const float* __restrict__ w,
    const float* __restrict__ w_dense, const float* __restrict__ b_mod,
    const float* __restrict__ w_conv, __bf16* __restrict__ xTg,
    __bf16* __restrict__ PWf) {
  __shared__ unsigned short buf[64 * XS];
  const int tid = threadIdx.x;
  const int bid = blockIdx.x;

  if (bid >= 2056) {
    // ---- pwfs role: 128 blocks, 4 waves each = one oc per wave ----
    const int bid2 = bid - 2056;
    const int b = bid2 >> 4;
    const int ocq = bid2 & 15;
    const int oc = ocq * 4 + (tid >> 6);
    const int ic = tid & 63;

    float stv = style_of(w, w_dense, b_mod, b, ic);
    float E[6][6];
    compute_E(w_conv, stv, oc, E);

    const int ks = ic >> 4;
    const int h = (ic >> 3) & 1;
    const int e = ic & 7;
    const int lane = (oc & 31) + 32 * h;
    const int ocg = oc >> 5;

    #pragma unroll
    for (int pp = 0; pp < 2; ++pp)
      #pragma unroll
      for (int pq = 0; pq < 2; ++pq) {
        const int ph = pp * 2 + pq;
        #pragma unroll
        for (int j = 0; j < 3; ++j)
          #pragma unroll
          for (int l = 0; l < 3; ++l) {
            const int tap = j * 3 + l;
            float val = E[2 * j + 1 - pp][2 * l + 1 - pq];
            size_t off =
                ((size_t)(((((b * 4 + ph) * 9 + tap) * 2 + ocg) * 4 + ks)) *
                     64 + lane) * 8 + e;
            PWf[off] = (__bf16)val;
          }
      }
    return;
  }

  // ---- xtp role ----
  const int m = bid % 257; // 0..256 ; 256 = guard-zero pass
  const int b = bid / 257;

  if (m == 256) {
    uint4 z = make_uint4(0, 0, 0, 0);
    for (int i = tid; i < 8224; i += 256) {
      int pix = i >> 3;
      int sub = i & 7;
      int pr, pc;
      if (pix < 258) {
        pr = 0; pc = pix;
      } else if (pix < 516) {
        pr = 257; pc = pix - 258;
      } else {
        int rem = pix - 516; // 0..511
        pr = 1 + (rem >> 1);
        pc = (rem & 1) ? 257 : 0;
      }
      *(uint4*)(xTg + ((size_t)(b * PP + pr) * PP + pc) * 64 + sub * 8) = z;
    }
    return;
  }

  const int ln = tid & 63, grp = tid >> 6;
  #pragma unroll
  for (int p = 0; p < 16; ++p) {
    const int ic = p * 4 + grp;
    float4 v = *(const float4*)(x + ((size_t)(b * 64 + ic) * 256 + m) * 256 +
                                ln * 4);
    ushort4 u4;
    u4.x = __builtin_bit_cast(unsigned short, (__bf16)v.x);
    u4.y = __builtin_bit_cast(unsigned short, (__bf16)v.y);
    u4.z = __builtin_bit_cast(unsigned short, (__bf16)v.z);
    u4.w = __builtin_bit_cast(unsigned short, (__bf16)v.w);
    *(ushort4*)&buf[ic * XS + ln * 4] = u4;
  }
  __syncthreads();
  #pragma unroll
  for (int it = 0; it < 8; ++it) {
    int pix = it * 32 + (tid >> 3);
    int g = tid & 7;
    bf16x8 o;
    #pragma unroll
    for (int e = 0; e < 8; ++e)
      o[e] = __builtin_bit_cast(__bf16, buf[(g * 8 + e) * XS + pix]);
    *(bf16x8*)(xTg + ((size_t)(b * PP + m + 1) * PP + (pix + 1)) * 64 +
               g * 8) = o;
  }
}

// ---- staging-free MFMA conv: B-fragments read directly from xTg via L1 ----
#define CMT 4

__global__ __launch_bounds__(512, 2) void conv32n_kernel(
    const __bf16* __restrict__ xTg, const __bf16* __restrict__ PWf,
    float* __restrict__ out) {
  __shared__ float xchg[8][64][18]; // 36864 B (pad-18: <=4-way)

  const int tid = threadIdx.x;
  const int lane = tid & 63;
  const int wv = tid >> 6; // 0..7
  const int pq = wv & 1;
  const int pp = (wv >> 1) & 1;
  const int og = wv >> 2;

  // XCD swizzle: each XCD owns one b (64 consecutive bids)
  const int raw = blockIdx.x; // 512 = 8b * 64mtile
  const int bid = (raw & 7) * 64 + (raw >> 3);
  const int mtile = bid & 63;
  const int b = bid >> 6;
  const int m0 = mtile * CMT;

  const int ln31 = lane & 31;
  const int lh = lane >> 5;
  const int ph = b * 4 + pp * 2 + pq;
  const bf16x8* Awave =
      (const bf16x8*)PWf + ((size_t)ph * 72 + og * 4) * 64 + lane;

  // ---- prologue: A fully register-resident (36 frags = 144 VGPR) ----
  bf16x8 A[9][4];
  #pragma unroll
  for (int tap = 0; tap < 9; ++tap)
    #pragma unroll
    for (int ks = 0; ks < 4; ++ks) A[tap][ks] = Awave[(tap * 8 + ks) * 64];

  #pragma unroll 1
  for (int t = 0; t < 8; ++t) {
    const int n0 = t * 32;
    // tile base (wave-uniform); rows m0..m0+5, cols n0..n0+33 of padded grid
    const __bf16* tb = xTg + ((size_t)(b * PP + m0) * PP + n0) * 64;

    f32x16 acc[4]; // 4 rows of own phase, 32 oc x 32 cols
    #pragma unroll
    for (int mw = 0; mw < 4; ++mw)
      #pragma unroll
      for (int e = 0; e < 16; ++e) acc[mw][e] = 0.f;

    #pragma unroll
    for (int ks = 0; ks < 4; ++ks) {
      #pragma unroll
      for (int l = 0; l < 3; ++l) {
        const int g8 = (ks * 2 + lh) * 8;
        bf16x8 Bf[6];
        #pragma unroll
        for (int r = 0; r < 6; ++r) {
          Bf[r] = *(const bf16x8*)(tb + ((size_t)(r * PP) + ln31 + l) * 64 +
                                   g8);
        }
        __builtin_amdgcn_s_setprio(1);
        #pragma unroll
        for (int r = 0; r < 6; ++r) {
          #pragma unroll
          for (int j = 0; j < 3; ++j) {
            const int mw = r - j;
            if (mw >= 0 && mw < 4) {
              acc[mw] = __builtin_amdgcn_mfma_f32_32x32x16_bf16(
                  A[j * 3 + l][ks], Bf[r], acc[mw], 0, 0, 0);
            }
          }
        }
        __builtin_amdgcn_s_setprio(0);
      }
    }

    // ---- epilogue: pq-pair exchange -> paired f32x2 (full-line) stores ----
    #pragma unroll
    for (int k = 0; k < 2; ++k) {
      const int mwG = (pq == 0) ? 2 + k : k; // give to partner
      const int mwO = (pq == 0) ? k : 2 + k; // own store rows
      #pragma unroll
      for (int q = 0; q < 8; ++q) {
        f32x2 s;
        s[0] = acc[mwG][2 * q];
        s[1] = acc[mwG][2 * q + 1];
        *(f32x2*)&xchg[wv][lane][2 * q] = s;
      }
      __builtin_amdgcn_s_barrier();
      float po[16];
      #pragma unroll
      for (int q = 0; q < 8; ++q) {
        f32x2 r = *(const f32x2*)&xchg[wv ^ 1][lane][2 * q];
        po[2 * q] = r[0];
        po[2 * q + 1] = r[1];
      }
      const int p = 2 * (m0 + mwO) + pp;
      #pragma unroll
      for (int rr = 0; rr < 16; ++rr) {
        const int oc_loc = (rr & 3) + 8 * (rr >> 2) + 4 * lh;
        const int oc = og * 32 + oc_loc;
        size_t off =
            ((size_t)(b * 64 + oc) * 512 + p) * 512 + 2 * (n0 + ln31);
        f32x2 v2;
        v2[0] = (pq == 0) ? acc[mwO][rr] : po[rr];
        v2[1] = (pq == 0) ? po[rr] : acc[mwO][rr];
        *(f32x2*)(out + off) = v2;
      }
      // protect xchg before the next write round / next tile
      if (k == 0 || t < 7) __builtin_amdgcn_s_barrier();
    }
  }
}

// ===================== fallback: f32 path =====================
__global__ __launch_bounds__(64) void pw_kernel(
    const float* __restrict__ w, const float* __restrict__ w_dense,
    const float* __restrict__ b_mod, const float* __restrict__ w_conv,
    float* __restrict__ PW) {
  const int oc = blockIdx.x;
  const int b = blockIdx.y;
  const int ic = threadIdx.x;
  float stv = style_of(w, w_dense, b_mod, b, ic);
  float E[6][6];
  compute_E(w_conv, stv, oc, E);
  #pragma unroll
  for (int pp = 0; pp < 2; ++pp)
    #pragma unroll
    for (int pq = 0; pq < 2; ++pq)
      #pragma unroll
      for (int j = 0; j < 3; ++j)
        #pragma unroll
        for (int l = 0; l < 3; ++l)
          PW[(((size_t)((b * 4 + pp * 2 + pq) * OC + oc) * IC + ic) * 9) +
             j * 3 + l] = E[2 * j + 1 - pp][2 * l + 1 - pq];
}

#define MT 16
#define NT 64
#define ICC 8
#define XROWS 18
#define XCOLS 66
#define XSTRIDE 68

__global__ __launch_bounds__(256) void conv_kernel(
    const float* __restrict__ x, const float* __restrict__ PW,
    float* __restrict__ out) {
  __shared__ float lds_x[ICC][XROWS][XSTRIDE];
  __shared__ float lds_w[4][ICC][9][4];

  const int tid = threadIdx.x;
  const int tn = tid & 15;
  const int tm = tid >> 4;
  const int bx = blockIdx.x;
  const int ntile = bx & 3;
  const int mtile = bx >> 2;
  const int ocg = blockIdx.y;
  const int b = blockIdx.z;
  const int m0 = mtile * MT;
  const int n0 = ntile * NT;

  float acc[4][4][4];
  #pragma unroll
  for (int o = 0; o < 4; ++o)
    #pragma unroll
    for (int ph = 0; ph < 4; ++ph)
      #pragma unroll
      for (int s = 0; s < 4; ++s) acc[o][ph][s] = 0.f;

  for (int ic0 = 0; ic0 < IC; ic0 += ICC) {
    __syncthreads();
    for (int ici = 0; ici < ICC; ++ici) {
      const float* xsrc = x + (size_t)(b * IC + ic0 + ici) * HH * HH;
      for (int rc = tid; rc < XROWS * XCOLS; rc += 256) {
        int r = rc / XCOLS;
        int c = rc - r * XCOLS;
        int gr = m0 - 1 + r;
        int gc = n0 - 1 + c;
        float v = 0.f;
        if ((unsigned)gr < HH && (unsigned)gc < HH) v = xsrc[gr * HH + gc];
        lds_x[ici][r][c] = v;
      }
    }
    for (int idx = tid; idx < 4 * ICC * 9 * 4; idx += 256) {
      int o = idx / (ICC * 9 * 4);
      int rem = idx - o * (ICC * 9 * 4);
      int ici = rem / 36;
      int r2 = rem - ici * 36;
      int t = r2 >> 2;
      int ph = r2 & 3;
      lds_w[o][ici][t][ph] =
          PW[(((size_t)((b * 4 + ph) * OC + (ocg * 4 + o)) * IC +
               (ic0 + ici)) * 9) + t];
    }
    __syncthreads();
    for (int ici = 0; ici < ICC; ++ici) {
      #pragma unroll
      for (int j = 0; j < 3; ++j) {
        const float* xr = &lds_x[ici][tm + j][tn * 4];
        float4 a4 = *(const float4*)xr;
        float2 a2 = *(const float2*)(xr + 4);
        float xv[6] = {a4.x, a4.y, a4.z, a4.w, a2.x, a2.y};
        #pragma unroll
        for (int l = 0; l < 3; ++l) {
          #pragma unroll
          for (int o = 0; o < 4; ++o) {
            float4 wv = *(const float4*)&lds_w[o][ici][j * 3 + l][0];
            #pragma unroll
            for (int s = 0; s < 4; ++s) {
              acc[o][0][s] = fmaf(wv.x, xv[l + s], acc[o][0][s]);
              acc[o][1][s] = fmaf(wv.y, xv[l + s], acc[o][1][s]);
              acc[o][2][s] = fmaf(wv.z, xv[l + s], acc[o][2][s]);
              acc[o][3][s] = fmaf(wv.w, xv[l + s], acc[o][3][s]);
            }
          }
        }
      }
    }
  }

  #pragma unroll
  for (int o = 0; o < 4; ++o) {
    #pragma unroll
    for (int pp = 0; pp < 2; ++pp) {
      const int p = 2 * (m0 + tm) + pp;
      float* dst = out +
          (((size_t)(b * OC + ocg * 4 + o) * 512 + p) * 512) + 2 * n0 + 8 * tn;
      float4 v0 = make_float4(acc[o][pp * 2 + 0][0], acc[o][pp * 2 + 1][0],
                              acc[o][pp * 2 + 0][1], acc[o][pp * 2 + 1][1]);
      float4 v1 = make_float4(acc[o][pp * 2 + 0][2], acc[o][pp * 2 + 1][2],
                              acc[o][pp * 2 + 0][3], acc[o][pp * 2 + 1][3]);
      *(float4*)dst = v0;
      *(float4*)(dst + 4) = v1;
    }
  }
}

extern "C" void kernel_launch(void* const* d_in, const int* in_sizes, int n_in,
                              void* d_out, int out_size, void* d_ws,
                              size_t ws_size, hipStream_t stream) {
  const float* x = (const float*)d_in[0];
  const float* w = (const float*)d_in[1];
  const float* w_conv = (const float*)d_in[2];
  const float* w_dense = (const float*)d_in[3];
  const float* b_mod = (const float*)d_in[4];
  float* out = (float*)d_out;

  const size_t PWF_BYTES = (size_t)8 * 4 * 9 * 2 * 4 * 64 * 8 * 2; // 2359296
  const size_t XTG_BYTES = (size_t)8 * PP * PP * 64 * 2;           // 68161536
  const size_t NEED_NEW = PWF_BYTES + XTG_BYTES;

  if (ws_size >= NEED_NEW) {
    __bf16* PWf = (__bf16*)d_ws;
    __bf16* xTg = (__bf16*)((char*)d_ws + PWF_BYTES);
    pre_kernel<<<dim3(2056 + 128), 256, 0, stream>>>(x, w, w_dense, b_mod,
                                                     w_conv, xTg, PWf);
    conv32n_kernel<<<dim3(512), 512, 0, stream>>>(xTg, PWf, out);
  } else {
    float* PW = (float*)d_ws;
    pw_kernel<<<dim3(OC, NB), 64, 0, stream>>>(w, w_dense, b_mod, w_conv, PW);
    conv_kernel<<<dim3(64, 16, NB), 256, 0, stream>>>(x, PW, out);
  }
}

// Round 13
// 250.261 us; speedup vs baseline: 1.6576x; 1.6576x over previous
//
#include <hip/hip_runtime.h>

#define NB 8
#define IC 64
#define OC 64
#define HH 256
#define WD 512
#define PP 258 // padded pitch

typedef __bf16 bf16x8 __attribute__((ext_vector_type(8)));
typedef float f32x16 __attribute__((ext_vector_type(16)));
typedef float f32x4 __attribute__((ext_vector_type(4)));

// Weight math: modulate, demodulate, compose with blur into E[6][6].
__device__ inline void compute_E(const float* __restrict__ w_conv, float stv,
                                 int oc, float E[6][6]) {
  const float coef_conv = 1.0f / 24.0f; // 1/sqrt(3*3*64)
  const float s = stv * coef_conv;
  const int ic = threadIdx.x & 63;

  float wm[3][3];
  float ssq = 0.f;
  #pragma unroll
  for (int kh = 0; kh < 3; ++kh)
    #pragma unroll
    for (int kw = 0; kw < 3; ++kw) {
      float v = w_conv[((kh * 3 + kw) * IC + ic) * OC + oc] * s;
      wm[kh][kw] = v;
      ssq += v * v;
    }
  #pragma unroll
  for (int off = 32; off > 0; off >>= 1) ssq += __shfl_xor(ssq, off);
  const float d = rsqrtf(ssq + 1e-8f);
  #pragma unroll
  for (int kh = 0; kh < 3; ++kh)
    #pragma unroll
    for (int kw = 0; kw < 3; ++kw) wm[kh][kw] *= d;

  const float g[4] = {0.25f, 0.75f, 0.75f, 0.25f};
  #pragma unroll
  for (int a = 0; a < 6; ++a)
    #pragma unroll
    for (int c = 0; c < 6; ++c) {
      float acc = 0.f;
      #pragma unroll
      for (int dh = 0; dh < 3; ++dh) {
        int u = a - dh;
        if (u < 0 || u > 3) continue;
        #pragma unroll
        for (int dw = 0; dw < 3; ++dw) {
          int v = c - dw;
          if (v < 0 || v > 3) continue;
          acc = fmaf(wm[dh][dw], g[u] * g[v], acc);
        }
      }
      E[a][c] = acc;
    }
}

__device__ inline float style_of(const float* __restrict__ w,
                                 const float* __restrict__ w_dense,
                                 const float* __restrict__ b_mod, int b,
                                 int ic) {
  const float coef_dense = 0.044194173824159216f; // 1/sqrt(512)
  const float* wr = w + b * WD;
  float acc = 0.f;
  for (int k = 0; k < WD; ++k) acc = fmaf(wr[k], w_dense[k * IC + ic], acc);
  return acc * coef_dense + b_mod[ic] + 1.0f;
}

// ---- fused pre-pass: xtp role (bid<2056) + pwfs role (bid>=2056) ----
#define XS 268 // u16 LDS stride
__global__ __launch_bounds__(256) void pre_kernel(
    const float* __restrict__ x, const float* __restrict__ w,
    const float* __restrict__ w_dense, const float* __restrict__ b_mod,
    const float* __restrict__ w_conv, __bf16* __restrict__ xTg,
    __bf16* __restrict__ PWf) {
  __shared__ unsigned short buf[64 * XS];
  const int tid = threadIdx.x;
  const int bid = blockIdx.x;

  if (bid >= 2056) {
    const int bid2 = bid - 2056;
    const int b = bid2 >> 4;
    const int ocq = bid2 & 15;
    const int oc = ocq * 4 + (tid >> 6);
    const int ic = tid & 63;

    float stv = style_of(w, w_dense, b_mod, b, ic);
    float E[6][6];
    compute_E(w_conv, stv, oc, E);

    const int ks = ic >> 4;
    const int h = (ic >> 3) & 1;
    const int e = ic & 7;
    const int lane = (oc & 31) + 32 * h;
    const int ocg = oc >> 5;

    #pragma unroll
    for (int pp = 0; pp < 2; ++pp)
      #pragma unroll
      for (int pq = 0; pq < 2; ++pq) {
        const int ph = pp * 2 + pq;
        #pragma unroll
        for (int j = 0; j < 3; ++j)
          #pragma unroll
          for (int l = 0; l < 3; ++l) {
            const int tap = j * 3 + l;
            float val = E[2 * j + 1 - pp][2 * l + 1 - pq];
            size_t off =
                ((size_t)(((((b * 4 + ph) * 9 + tap) * 2 + ocg) * 4 + ks)) *
                     64 + lane) * 8 + e;
            PWf[off] = (__bf16)val;
          }
      }
    return;
  }

  const int m = bid % 257; // 0..256 ; 256 = guard-zero pass
  const int b = bid / 257;

  if (m == 256) {
    uint4 z = make_uint4(0, 0, 0, 0);
    for (int i = tid; i < 8224; i += 256) {
      int pix = i >> 3;
      int sub = i & 7;
      int pr, pc;
      if (pix < 258) {
        pr = 0; pc = pix;
      } else if (pix < 516) {
        pr = 257; pc = pix - 258;
      } else {
        int rem = pix - 516; // 0..511
        pr = 1 + (rem >> 1);
        pc = (rem & 1) ? 257 : 0;
      }
      *(uint4*)(xTg + ((size_t)(b * PP + pr) * PP + pc) * 64 + sub * 8) = z;
    }
    return;
  }

  const int ln = tid & 63, grp = tid >> 6;
  #pragma unroll
  for (int p = 0; p < 16; ++p) {
    const int ic = p * 4 + grp;
    float4 v = *(const float4*)(x + ((size_t)(b * 64 + ic) * 256 + m) * 256 +
                                ln * 4);
    ushort4 u4;
    u4.x = __builtin_bit_cast(unsigned short, (__bf16)v.x);
    u4.y = __builtin_bit_cast(unsigned short, (__bf16)v.y);
    u4.z = __builtin_bit_cast(unsigned short, (__bf16)v.z);
    u4.w = __builtin_bit_cast(unsigned short, (__bf16)v.w);
    *(ushort4*)&buf[ic * XS + ln * 4] = u4;
  }
  __syncthreads();
  #pragma unroll
  for (int it = 0; it < 8; ++it) {
    int pix = it * 32 + (tid >> 3);
    int g = tid & 7;
    bf16x8 o;
    #pragma unroll
    for (int e = 0; e < 8; ++e)
      o[e] = __builtin_bit_cast(__bf16, buf[(g * 8 + e) * XS + pix]);
    *(bf16x8*)(xTg + ((size_t)(b * PP + m + 1) * PP + (pix + 1)) * 64 +
               g * 8) = o;
  }
}

// ---- full-row MFMA conv: per block (b, 2 m-rows, n-half), flush 1KB rows ----
#define GLD_LDS(src, dst)                                                \
  __builtin_amdgcn_global_load_lds(                                      \
      (const __attribute__((address_space(1))) void*)(src),              \
      (__attribute__((address_space(3))) void*)(dst), 16, 0, 0)

__global__ __launch_bounds__(512, 2) void conv32f_kernel(
    const __bf16* __restrict__ xTg, const __bf16* __restrict__ PWf,
    float* __restrict__ out) {
  // band: 4 rows x 130 cols x 8 granule-slots x 16B = 66560 B
  __shared__ __bf16 band[4 * 130 * 8 * 8];

  const int tid = threadIdx.x;
  const int lane = tid & 63;
  const int wv = tid >> 6; // 0..7
  const int pq = wv & 1;
  const int pp = (wv >> 1) & 1;
  const int og = wv >> 2;
  const int ln31 = lane & 31;
  const int lh = lane >> 5;

  // XCD swizzle: each XCD owns one b (256 consecutive bids)
  const int raw = blockIdx.x; // 2048 = 8b * 128mt * 2nh
  const int bid = (raw & 7) * 256 + (raw >> 3);
  const int nh = bid & 1;
  const int mt = (bid >> 1) & 127;
  const int b = bid >> 8;
  const int mr = mt * 2; // input rows mr, mr+1

  const int ph = b * 4 + pp * 2 + pq;
  const bf16x8* Awave =
      (const bf16x8*)PWf + ((size_t)ph * 72 + og * 4) * 64 + lane;

  // ---- stage band: padded rows mr..mr+3, padded cols nh*128..+129 ----
  // linear chunk L = (row*130 + col)*8 + slot ; slot holds granule
  // slot^(col&7) (reader XOR). 4160 chunks, wave w owns [w*520, w*520+520).
  {
    const int wb = wv * 520;
    #pragma unroll
    for (int it = 0; it < 9; ++it) {
      int o = it * 64 + lane;
      if (o < 520) {
        int L = wb + o;
        int row = L / 1040;
        int rem = L - row * 1040;
        int col = rem >> 3;
        int s = rem & 7;
        int g = s ^ (col & 7);
        const __bf16* src =
            xTg + ((size_t)(b * PP + mr + row) * PP + nh * 128 + col) * 64 +
            g * 8;
        GLD_LDS(src, band + (size_t)L * 8);
      }
    }
  }
  asm volatile("s_waitcnt vmcnt(0)" ::: "memory");
  __builtin_amdgcn_s_barrier();

  // ---- compute: acc[mw][nsub] over 2 m-rows x 4 n-subtiles ----
  f32x16 acc[2][4];
  #pragma unroll
  for (int mw = 0; mw < 2; ++mw)
    #pragma unroll
    for (int ns = 0; ns < 4; ++ns)
      #pragma unroll
      for (int e = 0; e < 16; ++e) acc[mw][ns][e] = 0.f;

  #pragma unroll
  for (int ks = 0; ks < 4; ++ks) {
    #pragma unroll
    for (int l = 0; l < 3; ++l) {
      bf16x8 Ac[3];
      #pragma unroll
      for (int j = 0; j < 3; ++j) Ac[j] = Awave[((j * 3 + l) * 8 + ks) * 64];

      #pragma unroll
      for (int ns = 0; ns < 4; ++ns) {
        const int cc = ns * 32 + ln31 + l;
        const int slot = (ks * 2 + lh) ^ (cc & 7);
        bf16x8 Bf[4];
        #pragma unroll
        for (int r = 0; r < 4; ++r)
          Bf[r] = *(const bf16x8*)(band + ((size_t)((r * 130 + cc) * 8 +
                                                    slot)) * 8);
        __builtin_amdgcn_s_setprio(1);
        #pragma unroll
        for (int r = 0; r < 4; ++r) {
          #pragma unroll
          for (int j = 0; j < 3; ++j) {
            const int mw = r - j;
            if (mw == 0 || mw == 1) {
              acc[mw][ns] = __builtin_amdgcn_mfma_f32_32x32x16_bf16(
                  Ac[j], Bf[r], acc[mw][ns], 0, 0, 0);
            }
          }
        }
        __builtin_amdgcn_s_setprio(0);
      }
    }
  }

  // ---- flush: overlay fb on dead band; 8 rounds (mw, eg) ----
  // fb[pair(pp,og)=4][ocb=8][260] f32 ; emit 1KB-contiguous rows.
  __builtin_amdgcn_s_barrier(); // all compute reads of band done
  float* fb = (float*)band;     // 33280 B used <= 66560
  const int pid = wv >> 1;      // pp + 2*og

  #pragma unroll
  for (int mw = 0; mw < 2; ++mw) {
    #pragma unroll
    for (int eg = 0; eg < 4; ++eg) {
      // deposit own 4 e-values x 4 nsub
      #pragma unroll
      for (int i = 0; i < 4; ++i) {
        const int e = eg * 4 + i;
        const int ocb = i + 4 * lh;
        #pragma unroll
        for (int ns = 0; ns < 4; ++ns) {
          fb[(pid * 8 + ocb) * 260 + ns * 64 + 2 * ln31 + pq] =
              acc[mw][ns][e];
        }
      }
      __builtin_amdgcn_s_barrier();
      // emit: wave handles 4 of the 32 rows
      #pragma unroll
      for (int rro = 0; rro < 4; ++rro) {
        const int row = wv * 4 + rro;
        const int pid2 = row >> 3;
        const int ocb2 = row & 7;
        const int og2 = pid2 >> 1;
        const int pp2 = pid2 & 1;
        const int oc = og2 * 32 + (ocb2 & 3) + 8 * eg + 4 * (ocb2 >> 2);
        const int p = 2 * (mr + mw) + pp2;
        f32x4 v = *(const f32x4*)&fb[row * 260 + lane * 4];
        *(f32x4*)(out + ((size_t)(b * 64 + oc) * 512 + p) * 512 + nh * 256 +
                  lane * 4) = v;
      }
      __builtin_amdgcn_s_barrier();
    }
  }
}

// ===================== fallback: f32 path =====================
__global__ __launch_bounds__(64) void pw_kernel(
    const float* __restrict__ w, const float* __restrict__ w_dense,
    const float* __restrict__ b_mod, const float* __restrict__ w_conv,
    float* __restrict__ PW) {
  const int oc = blockIdx.x;
  const int b = blockIdx.y;
  const int ic = threadIdx.x;
  float stv = style_of(w, w_dense, b_mod, b, ic);
  float E[6][6];
  compute_E(w_conv, stv, oc, E);
  #pragma unroll
  for (int pp = 0; pp < 2; ++pp)
    #pragma unroll
    for (int pq = 0; pq < 2; ++pq)
      #pragma unroll
      for (int j = 0; j < 3; ++j)
        #pragma unroll
        for (int l = 0; l < 3; ++l)
          PW[(((size_t)((b * 4 + pp * 2 + pq) * OC + oc) * IC + ic) * 9) +
             j * 3 + l] = E[2 * j + 1 - pp][2 * l + 1 - pq];
}

#define MT 16
#define NT 64
#define ICC 8
#define XROWS 18
#define XCOLS 66
#define XSTRIDE 68

__global__ __launch_bounds__(256) void conv_kernel(
    const float* __restrict__ x, const float* __restrict__ PW,
    float* __restrict__ out) {
  __shared__ float lds_x[ICC][XROWS][XSTRIDE];
  __shared__ float lds_w[4][ICC][9][4];

  const int tid = threadIdx.x;
  const int tn = tid & 15;
  const int tm = tid >> 4;
  const int bx = blockIdx.x;
  const int ntile = bx & 3;
  const int mtile = bx >> 2;
  const int ocg = blockIdx.y;
  const int b = blockIdx.z;
  const int m0 = mtile * MT;
  const int n0 = ntile * NT;

  float acc[4][4][4];
  #pragma unroll
  for (int o = 0; o < 4; ++o)
    #pragma unroll
    for (int ph = 0; ph < 4; ++ph)
      #pragma unroll
      for (int s = 0; s < 4; ++s) acc[o][ph][s] = 0.f;

  for (int ic0 = 0; ic0 < IC; ic0 += ICC) {
    __syncthreads();
    for (int ici = 0; ici < ICC; ++ici) {
      const float* xsrc = x + (size_t)(b * IC + ic0 + ici) * HH * HH;
      for (int rc = tid; rc < XROWS * XCOLS; rc += 256) {
        int r = rc / XCOLS;
        int c = rc - r * XCOLS;
        int gr = m0 - 1 + r;
        int gc = n0 - 1 + c;
        float v = 0.f;
        if ((unsigned)gr < HH && (unsigned)gc < HH) v = xsrc[gr * HH + gc];
        lds_x[ici][r][c] = v;
      }
    }
    for (int idx = tid; idx < 4 * ICC * 9 * 4; idx += 256) {
      int o = idx / (ICC * 9 * 4);
      int rem = idx - o * (ICC * 9 * 4);
      int ici = rem / 36;
      int r2 = rem - ici * 36;
      int t = r2 >> 2;
      int ph = r2 & 3;
      lds_w[o][ici][t][ph] =
          PW[(((size_t)((b * 4 + ph) * OC + (ocg * 4 + o)) * IC +
               (ic0 + ici)) * 9) + t];
    }
    __syncthreads();
    for (int ici = 0; ici < ICC; ++ici) {
      #pragma unroll
      for (int j = 0; j < 3; ++j) {
        const float* xr = &lds_x[ici][tm + j][tn * 4];
        float4 a4 = *(const float4*)xr;
        float2 a2 = *(const float2*)(xr + 4);
        float xv[6] = {a4.x, a4.y, a4.z, a4.w, a2.x, a2.y};
        #pragma unroll
        for (int l = 0; l < 3; ++l) {
          #pragma unroll
          for (int o = 0; o < 4; ++o) {
            float4 wv = *(const float4*)&lds_w[o][ici][j * 3 + l][0];
            #pragma unroll
            for (int s = 0; s < 4; ++s) {
              acc[o][0][s] = fmaf(wv.x, xv[l + s], acc[o][0][s]);
              acc[o][1][s] = fmaf(wv.y, xv[l + s], acc[o][1][s]);
              acc[o][2][s] = fmaf(wv.z, xv[l + s], acc[o][2][s]);
              acc[o][3][s] = fmaf(wv.w, xv[l + s], acc[o][3][s]);
            }
          }
        }
      }
    }
  }

  #pragma unroll
  for (int o = 0; o < 4; ++o) {
    #pragma unroll
    for (int pp = 0; pp < 2; ++pp) {
      const int p = 2 * (m0 + tm) + pp;
      float* dst = out +
          (((size_t)(b * OC + ocg * 4 + o) * 512 + p) * 512) + 2 * n0 + 8 * tn;
      float4 v0 = make_float4(acc[o][pp * 2 + 0][0], acc[o][pp * 2 + 1][0],
                              acc[o][pp * 2 + 0][1], acc[o][pp * 2 + 1][1]);
      float4 v1 = make_float4(acc[o][pp * 2 + 0][2], acc[o][pp * 2 + 1][2],
                              acc[o][pp * 2 + 0][3], acc[o][pp * 2 + 1][3]);
      *(float4*)dst = v0;
      *(float4*)(dst + 4) = v1;
    }
  }
}

extern "C" void kernel_launch(void* const* d_in, const int* in_sizes, int n_in,
                              void* d_out, int out_size, void* d_ws,
                              size_t ws_size, hipStream_t stream) {
  const float* x = (const float*)d_in[0];
  const float* w = (const float*)d_in[1];
  const float* w_conv = (const float*)d_in[2];
  const float* w_dense = (const float*)d_in[3];
  const float* b_mod = (const float*)d_in[4];
  float* out = (float*)d_out;

  const size_t PWF_BYTES = (size_t)8 * 4 * 9 * 2 * 4 * 64 * 8 * 2; // 2359296
  const size_t XTG_BYTES = (size_t)8 * PP * PP * 64 * 2;           // 68161536
  const size_t NEED_NEW = PWF_BYTES + XTG_BYTES;

  if (ws_size >= NEED_NEW) {
    __bf16* PWf = (__bf16*)d_ws;
    __bf16* xTg = (__bf16*)((char*)d_ws + PWF_BYTES);
    pre_kernel<<<dim3(2056 + 128), 256, 0, stream>>>(x, w, w_dense, b_mod,
                                                     w_conv, xTg, PWf);
    conv32f_kernel<<<dim3(2048), 512, 0, stream>>>(xTg, PWf, out);
  } else {
    float* PW = (float*)d_ws;
    pw_kernel<<<dim3(OC, NB), 64, 0, stream>>>(w, w_dense, b_mod, w_conv, PW);
    conv_kernel<<<dim3(64, 16, NB), 256, 0, stream>>>(x, PW, out);
  }
}